// Round 6
// baseline (456.617 us; speedup 1.0000x reference)
//
#include <hip/hip_runtime.h>

#define DH 128

typedef __attribute__((ext_vector_type(8))) short short8;
typedef __attribute__((ext_vector_type(4))) float f32x4;

// ---------- helpers ----------
__device__ __forceinline__ float wave_sum(float v) {
    #pragma unroll
    for (int o = 32; o > 0; o >>= 1) v += __shfl_xor(v, o, 64);
    return v;
}

__device__ __forceinline__ void ln_pair(float v0, float v1, float& o0, float& o1) {
    float m = wave_sum(v0 + v1) * (1.f / 128.f);
    float d0 = v0 - m, d1 = v1 - m;
    float var = wave_sum(d0 * d0 + d1 * d1) * (1.f / 128.f);
    float inv = rsqrtf(var + 1e-5f);
    o0 = d0 * inv; o1 = d1 * inv;
}

__device__ __forceinline__ float elu(float x) { return x > 0.f ? x : expm1f(x); }

// fp32 -> bf16 round-to-nearest-even
__device__ __forceinline__ unsigned short f2bf(float f) {
    unsigned u = __float_as_uint(f);
    u += 0x7fffu + ((u >> 16) & 1u);
    return (unsigned short)(u >> 16);
}
__device__ __forceinline__ float bfl(unsigned u) { return __uint_as_float(u << 16); }
__device__ __forceinline__ float bfh(unsigned u) { return __uint_as_float(u & 0xffff0000u); }
__device__ __forceinline__ unsigned pack_bf2(float a, float b) {
    return (unsigned)f2bf(a) | ((unsigned)f2bf(b) << 16);
}
__device__ __forceinline__ short8 cvt8(float4 v0, float4 v1) {
    short8 o;
    o[0] = (short)f2bf(v0.x); o[1] = (short)f2bf(v0.y);
    o[2] = (short)f2bf(v0.z); o[3] = (short)f2bf(v0.w);
    o[4] = (short)f2bf(v1.x); o[5] = (short)f2bf(v1.y);
    o[6] = (short)f2bf(v1.z); o[7] = (short)f2bf(v1.w);
    return o;
}

// ---------- streaming fp32 -> bf16 conversion of x ----------
__global__ __launch_bounds__(256) void conv_x_k(const float* __restrict__ x,
                                                unsigned short* __restrict__ xb,
                                                long long n8)
{
    long long i = (long long)blockIdx.x * 256 + threadIdx.x;
    long long stride = (long long)gridDim.x * 256;
    for (; i < n8; i += stride) {
        float4 v0 = *(const float4*)(x + i * 8);
        float4 v1 = *(const float4*)(x + i * 8 + 4);
        *(short8*)(xb + i * 8) = cvt8(v0, v1);
    }
}

// ---------- utility kernels ----------
__global__ void zero_int_k(int* __restrict__ p, int n) {
    int i = blockIdx.x * 256 + threadIdx.x;
    if (i < n) p[i] = 0;
}

__global__ void deg_count_k(const int* __restrict__ dst, int* __restrict__ deg, int E) {
    int e = blockIdx.x * 256 + threadIdx.x;
    if (e < E) atomicAdd(&deg[dst[e]], 1);
}

__global__ void dinv_k(const int* __restrict__ deg, float* __restrict__ dinv, int n) {
    int i = blockIdx.x * 256 + threadIdx.x;
    if (i < n) dinv[i] = rsqrtf((float)(deg[i] + 1));  // +1 self-loop
}

// ---------- parallel exclusive scan (3 kernels) ----------
__global__ __launch_bounds__(1024) void scan_part_k(const int* __restrict__ deg,
                                                    int* __restrict__ rowptr,
                                                    int* __restrict__ bsum, int n)
{
    __shared__ int wsum[16];
    const int tid = threadIdx.x, lane = tid & 63, wid = tid >> 6;
    int i = blockIdx.x * 1024 + tid;
    int v = (i < n) ? deg[i] : 0;
    int s = v;
    #pragma unroll
    for (int o = 1; o < 64; o <<= 1) {
        int t = __shfl_up(s, o, 64);
        if (lane >= o) s += t;
    }
    if (lane == 63) wsum[wid] = s;
    __syncthreads();
    if (tid < 16) {
        int ws = wsum[tid];
        #pragma unroll
        for (int o = 1; o < 16; o <<= 1) {
            int t = __shfl_up(ws, o, 64);
            if (tid >= o) ws += t;
        }
        wsum[tid] = ws;
    }
    __syncthreads();
    int excl = (wid ? wsum[wid - 1] : 0) + s - v;
    if (i < n) rowptr[i] = excl;
    if (tid == 0) bsum[blockIdx.x] = wsum[15];
}

__global__ void scan_top_k(int* __restrict__ bsum, int* __restrict__ rowptr_n, int nb) {
    int lane = threadIdx.x;  // blockDim = 64
    int carry = 0;
    for (int base = 0; base < nb; base += 64) {
        int i = base + lane;
        int v = (i < nb) ? bsum[i] : 0;
        int s = v;
        #pragma unroll
        for (int o = 1; o < 64; o <<= 1) {
            int t = __shfl_up(s, o, 64);
            if (lane >= o) s += t;
        }
        if (i < nb) bsum[i] = carry + s - v;
        carry += __shfl(s, 63, 64);
    }
    if (lane == 0) *rowptr_n = carry;
}

__global__ void scan_add_k(const int* __restrict__ bsum, int* __restrict__ rowptr,
                           int* __restrict__ cursor, int n)
{
    int i = blockIdx.x * 256 + threadIdx.x;
    if (i < n) {
        int v = rowptr[i] + bsum[i >> 10];
        rowptr[i] = v;
        cursor[i] = v;
    }
}

__global__ void fill_k(const int* __restrict__ src, const int* __restrict__ dst,
                       const float* __restrict__ dinv, int* __restrict__ cursor,
                       int2* __restrict__ csr, int E)
{
    int e = blockIdx.x * 256 + threadIdx.x;
    if (e < E) {
        int s = src[e], d = dst[e];
        float w = dinv[s] * dinv[d];
        int p = atomicAdd(&cursor[d], 1);
        csr[p] = make_int2(s, __float_as_int(w));
    }
}

// repack all four W's fp32 -> bf16 fragment panels [kb][n][32] into one buffer
// layout: Wp1 @0 (49152), Wpr @49152, Wp2 @98304 (16384), WpM @114688
__global__ void repack_all_k(const float* __restrict__ W1, const float* __restrict__ rW,
                             const float* __restrict__ W2, const float* __restrict__ mW1,
                             unsigned short* __restrict__ Wp)
{
    int idx = blockIdx.x * 256 + threadIdx.x;
    if (idx >= 131072) return;
    const float* W; int base;
    if (idx < 49152)       { W = W1;  base = 0; }
    else if (idx < 98304)  { W = rW;  base = 49152; }
    else if (idx < 114688) { W = W2;  base = 98304; }
    else                   { W = mW1; base = 114688; }
    int l = idx - base;
    int kb = l >> 12, rem = l & 4095;
    int nn = rem >> 5, ki = rem & 31;
    Wp[idx] = f2bf(W[(kb * 32 + ki) * DH + nn]);
}

// ---------- LDS-free MFMA GEMM, bf16 A, depth-2 A prefetch ----------
// grid (ceil(n/128), 2). Wave w: rows bx*128 + w*32 .. +32, cols by*64 .. +64.
template<int K, bool DUAL>
__global__ __launch_bounds__(256) void mfma_gemm(
    const unsigned short* __restrict__ A,
    const unsigned short* __restrict__ Bp1, const float* __restrict__ ba,
    const unsigned short* __restrict__ Bp2, const float* __restrict__ bb,
    unsigned short* __restrict__ outa, unsigned short* __restrict__ outb, int n)
{
    constexpr int NKB = K / 32;
    const int tid = threadIdx.x;
    const int wid = tid >> 6, lane = tid & 63;
    const int m16 = lane & 15, q = lane >> 4;
    const long long rb0 = (long long)blockIdx.x * 128 + wid * 32;
    const int colb = blockIdx.y * 64;

    long long r0 = rb0 + m16;      if (r0 > (long long)n - 1) r0 = n - 1;
    long long r1 = rb0 + 16 + m16; if (r1 > (long long)n - 1) r1 = n - 1;

    f32x4 acc1[2][4], acc2[2][4];
    const f32x4 zero = {0.f, 0.f, 0.f, 0.f};
    #pragma unroll
    for (int i = 0; i < 2; i++)
        #pragma unroll
        for (int j = 0; j < 4; j++) { acc1[i][j] = zero; if constexpr (DUAL) acc2[i][j] = zero; }

    short8 ha[3][2];            // A: 3 rotating buffers (depth-2 prefetch)
    short8 pb1[2][4], pb2[2][4]; // B: 2 buffers (depth-1)

    auto fetchA = [&](int kb, int buf) {
        ha[buf][0] = *(const short8*)(A + r0 * K + kb * 32 + q * 8);
        ha[buf][1] = *(const short8*)(A + r1 * K + kb * 32 + q * 8);
    };
    auto fetchB = [&](int kb, int buf) {
        #pragma unroll
        for (int nj = 0; nj < 4; ++nj) {
            long long boff = ((long long)kb * 128 + colb + nj * 16 + m16) * 32 + q * 8;
            pb1[buf][nj] = *(const short8*)(Bp1 + boff);
            if constexpr (DUAL) pb2[buf][nj] = *(const short8*)(Bp2 + boff);
        }
    };

    fetchA(0, 0);
    fetchB(0, 0);
    if constexpr (NKB > 1) fetchA(1, 1);

    #pragma unroll
    for (int kb = 0; kb < NKB; ++kb) {
        if (kb + 2 < NKB) fetchA(kb + 2, (kb + 2) % 3);
        if (kb + 1 < NKB) fetchB(kb + 1, (kb + 1) & 1);
        const int ca = kb % 3, cb = kb & 1;
        #pragma unroll
        for (int mi = 0; mi < 2; ++mi)
            #pragma unroll
            for (int nj = 0; nj < 4; ++nj) {
                acc1[mi][nj] = __builtin_amdgcn_mfma_f32_16x16x32_bf16(ha[ca][mi], pb1[cb][nj], acc1[mi][nj], 0, 0, 0);
                if constexpr (DUAL)
                    acc2[mi][nj] = __builtin_amdgcn_mfma_f32_16x16x32_bf16(ha[ca][mi], pb2[cb][nj], acc2[mi][nj], 0, 0, 0);
            }
    }

    // epilogue: C/D layout col=lane&15, row=(lane>>4)*4+reg; bf16 stores
    #pragma unroll
    for (int nj = 0; nj < 4; ++nj) {
        int col = colb + nj * 16 + m16;
        float bav = ba ? ba[col] : 0.f;
        float bbv = 0.f;
        if constexpr (DUAL) bbv = bb ? bb[col] : 0.f;
        #pragma unroll
        for (int mi = 0; mi < 2; ++mi) {
            long long row0 = rb0 + mi * 16 + q * 4;
            #pragma unroll
            for (int r = 0; r < 4; ++r) {
                long long rr = row0 + r;
                if (rr < n) {
                    outa[rr * DH + col] = f2bf(acc1[mi][nj][r] + bav);
                    if constexpr (DUAL) outb[rr * DH + col] = f2bf(acc2[mi][nj][r] + bbv);
                }
            }
        }
    }
}

// ---------- CSR gather (bf16 rows), one wave per row, 8 loads in flight ----------
__device__ __forceinline__ void gather_row(
    const unsigned* __restrict__ hw, const int2* __restrict__ csr,
    int beg, int end, int lane, float& o0, float& o1)
{
    float a0 = 0.f, a1 = 0.f, b0 = 0.f, b1 = 0.f;
    float c0 = 0.f, c1 = 0.f, d0 = 0.f, d1 = 0.f;
    int p = beg;
    for (; p + 7 < end; p += 8) {
        int2 e0 = csr[p],     e1 = csr[p + 1], e2 = csr[p + 2], e3 = csr[p + 3];
        int2 e4 = csr[p + 4], e5 = csr[p + 5], e6 = csr[p + 6], e7 = csr[p + 7];
        unsigned u0 = hw[(long long)e0.x * 64 + lane];
        unsigned u1 = hw[(long long)e1.x * 64 + lane];
        unsigned u2 = hw[(long long)e2.x * 64 + lane];
        unsigned u3 = hw[(long long)e3.x * 64 + lane];
        unsigned u4 = hw[(long long)e4.x * 64 + lane];
        unsigned u5 = hw[(long long)e5.x * 64 + lane];
        unsigned u6 = hw[(long long)e6.x * 64 + lane];
        unsigned u7 = hw[(long long)e7.x * 64 + lane];
        float w0 = __int_as_float(e0.y), w1 = __int_as_float(e1.y);
        float w2 = __int_as_float(e2.y), w3 = __int_as_float(e3.y);
        float w4 = __int_as_float(e4.y), w5 = __int_as_float(e5.y);
        float w6 = __int_as_float(e6.y), w7 = __int_as_float(e7.y);
        a0 = fmaf(w0, bfl(u0), a0);  a1 = fmaf(w0, bfh(u0), a1);
        b0 = fmaf(w1, bfl(u1), b0);  b1 = fmaf(w1, bfh(u1), b1);
        c0 = fmaf(w2, bfl(u2), c0);  c1 = fmaf(w2, bfh(u2), c1);
        d0 = fmaf(w3, bfl(u3), d0);  d1 = fmaf(w3, bfh(u3), d1);
        a0 = fmaf(w4, bfl(u4), a0);  a1 = fmaf(w4, bfh(u4), a1);
        b0 = fmaf(w5, bfl(u5), b0);  b1 = fmaf(w5, bfh(u5), b1);
        c0 = fmaf(w6, bfl(u6), c0);  c1 = fmaf(w6, bfh(u6), c1);
        d0 = fmaf(w7, bfl(u7), d0);  d1 = fmaf(w7, bfh(u7), d1);
    }
    for (; p + 3 < end; p += 4) {
        int2 e0 = csr[p], e1 = csr[p + 1], e2 = csr[p + 2], e3 = csr[p + 3];
        unsigned u0 = hw[(long long)e0.x * 64 + lane];
        unsigned u1 = hw[(long long)e1.x * 64 + lane];
        unsigned u2 = hw[(long long)e2.x * 64 + lane];
        unsigned u3 = hw[(long long)e3.x * 64 + lane];
        float w0 = __int_as_float(e0.y), w1 = __int_as_float(e1.y);
        float w2 = __int_as_float(e2.y), w3 = __int_as_float(e3.y);
        a0 = fmaf(w0, bfl(u0), a0);  a1 = fmaf(w0, bfh(u0), a1);
        b0 = fmaf(w1, bfl(u1), b0);  b1 = fmaf(w1, bfh(u1), b1);
        c0 = fmaf(w2, bfl(u2), c0);  c1 = fmaf(w2, bfh(u2), c1);
        d0 = fmaf(w3, bfl(u3), d0);  d1 = fmaf(w3, bfh(u3), d1);
    }
    for (; p < end; ++p) {
        int2 e0 = csr[p];
        unsigned u0 = hw[(long long)e0.x * 64 + lane];
        float w0 = __int_as_float(e0.y);
        a0 = fmaf(w0, bfl(u0), a0);
        a1 = fmaf(w0, bfh(u0), a1);
    }
    o0 = (a0 + b0) + (c0 + d0);
    o1 = (a1 + b1) + (c1 + d1);
}

// layer 1: h = elu(LN(gather + dinv^2*hw + b1)) + LN(proj)
__global__ __launch_bounds__(256) void gfuse1_k(
    const unsigned* __restrict__ hw, const unsigned* __restrict__ proj,
    const int* __restrict__ rowptr, const int2* __restrict__ csr,
    const float* __restrict__ dinv,
    const float* __restrict__ b1, const float* __restrict__ g1, const float* __restrict__ be1,
    const float* __restrict__ rg, const float* __restrict__ rbe,
    unsigned* __restrict__ hout, int n)
{
    int row = blockIdx.x * 4 + (threadIdx.x >> 6);
    if (row >= n) return;
    int lane = threadIdx.x & 63;
    float a0, a1;
    gather_row(hw, csr, rowptr[row], rowptr[row + 1], lane, a0, a1);
    long long off = (long long)row * 64;
    float di = dinv[row], sl = di * di;
    unsigned us = hw[off + lane];
    float2 bv  = *(const float2*)(b1 + 2 * lane);
    float2 gv  = *(const float2*)(g1 + 2 * lane);
    float2 bev = *(const float2*)(be1 + 2 * lane);
    float2 rgv = *(const float2*)(rg + 2 * lane);
    float2 rbv = *(const float2*)(rbe + 2 * lane);
    float v0 = a0 + sl * bfl(us) + bv.x;
    float v1 = a1 + sl * bfh(us) + bv.y;
    float o0, o1; ln_pair(v0, v1, o0, o1);
    float t0 = elu(o0 * gv.x + bev.x);
    float t1 = elu(o1 * gv.y + bev.y);
    unsigned up = proj[off + lane];
    float q0, q1; ln_pair(bfl(up), bfh(up), q0, q1);
    hout[off + lane] = pack_bf2(t0 + q0 * rgv.x + rbv.x, t1 + q1 * rgv.y + rbv.y);
}

// layer 2: h2 = elu(LN(gather + dinv^2*hw + b2)) + hprev
__global__ __launch_bounds__(256) void gfuse2_k(
    const unsigned* __restrict__ hw, const unsigned* __restrict__ hprev,
    const int* __restrict__ rowptr, const int2* __restrict__ csr,
    const float* __restrict__ dinv,
    const float* __restrict__ b2, const float* __restrict__ g2, const float* __restrict__ be2,
    unsigned* __restrict__ h2, int n)
{
    int row = blockIdx.x * 4 + (threadIdx.x >> 6);
    if (row >= n) return;
    int lane = threadIdx.x & 63;
    float a0, a1;
    gather_row(hw, csr, rowptr[row], rowptr[row + 1], lane, a0, a1);
    long long off = (long long)row * 64;
    float di = dinv[row], sl = di * di;
    unsigned us = hw[off + lane];
    float2 bv  = *(const float2*)(b2 + 2 * lane);
    float2 gv  = *(const float2*)(g2 + 2 * lane);
    float2 bev = *(const float2*)(be2 + 2 * lane);
    float v0 = a0 + sl * bfl(us) + bv.x;
    float v1 = a1 + sl * bfh(us) + bv.y;
    float o0, o1; ln_pair(v0, v1, o0, o1);
    float t0 = elu(o0 * gv.x + bev.x);
    float t1 = elu(o1 * gv.y + bev.y);
    unsigned uh = hprev[off + lane];
    h2[off + lane] = pack_bf2(t0 + bfl(uh), t1 + bfh(uh));
}

// ---------- head: LN+ELU on zraw, z @ mW2 + mb2, softmax K=16 (fused) ----------
__global__ __launch_bounds__(256) void head_k(
    const unsigned* __restrict__ zraw, const float* __restrict__ g, const float* __restrict__ be,
    const float* __restrict__ mW2, const float* __restrict__ mb2,
    float* __restrict__ out, int n)
{
    int row = blockIdx.x * 4 + (threadIdx.x >> 6);
    if (row >= n) return;
    int lane = threadIdx.x & 63;
    unsigned u = zraw[(long long)row * 64 + lane];
    float o0, o1; ln_pair(bfl(u), bfh(u), o0, o1);
    float2 gv  = *(const float2*)(g + 2 * lane);
    float2 bev = *(const float2*)(be + 2 * lane);
    float z0 = elu(o0 * gv.x + bev.x);
    float z1 = elu(o1 * gv.y + bev.y);
    int k = lane & 15, seg = lane >> 4;
    float acc = 0.f;
    #pragma unroll
    for (int t = 0; t < 16; ++t) {
        int srcl = seg * 16 + t;
        float zz0 = __shfl(z0, srcl, 64);
        float zz1 = __shfl(z1, srcl, 64);
        int c = seg * 32 + 2 * t;
        acc = fmaf(zz0, mW2[c * 16 + k], acc);
        acc = fmaf(zz1, mW2[(c + 1) * 16 + k], acc);
    }
    acc += __shfl_xor(acc, 32, 64);
    acc += __shfl_xor(acc, 16, 64);
    float hk = acc + mb2[k];
    float mx = hk;
    #pragma unroll
    for (int o = 8; o > 0; o >>= 1) mx = fmaxf(mx, __shfl_xor(mx, o, 64));
    float e = expf(hk - mx);
    float s = e;
    #pragma unroll
    for (int o = 8; o > 0; o >>= 1) s += __shfl_xor(s, o, 64);
    if (lane < 16) out[(long long)row * 16 + k] = e / s;
}

// ---------- launcher ----------
static inline size_t align16(size_t x) { return (x + 15) & ~(size_t)15; }

extern "C" void kernel_launch(void* const* d_in, const int* in_sizes, int n_in,
                              void* d_out, int out_size, void* d_ws, size_t ws_size,
                              hipStream_t stream)
{
    const float* x   = (const float*)d_in[0];
    const int*   ei  = (const int*)d_in[1];
    const float* W1  = (const float*)d_in[2];
    const float* b1  = (const float*)d_in[3];
    const float* g1  = (const float*)d_in[4];
    const float* be1 = (const float*)d_in[5];
    const float* W2  = (const float*)d_in[6];
    const float* b2  = (const float*)d_in[7];
    const float* g2  = (const float*)d_in[8];
    const float* be2 = (const float*)d_in[9];
    const float* rW  = (const float*)d_in[10];
    const float* rb  = (const float*)d_in[11];
    const float* rg  = (const float*)d_in[12];
    const float* rbe = (const float*)d_in[13];
    const float* mW1 = (const float*)d_in[14];
    const float* mb1 = (const float*)d_in[15];
    const float* mg  = (const float*)d_in[16];
    const float* mbe = (const float*)d_in[17];
    const float* mW2 = (const float*)d_in[18];
    const float* mb2 = (const float*)d_in[19];
    float* out = (float*)d_out;

    const int n = in_sizes[0] / 384;
    const int E = in_sizes[1] / 2;
    const int* src = ei;
    const int* dst = ei + E;

    char* w = (char*)d_ws;
    int* deg     = (int*)w;   w += align16((size_t)n * 4);
    int* rowptr  = (int*)w;   w += align16((size_t)(n + 1) * 4);
    int* cursor  = (int*)w;   w += align16((size_t)n * 4);
    float* dinv  = (float*)w; w += align16((size_t)n * 4);
    int* bsum    = (int*)w;   w += align16((size_t)1024 * 4);
    int2* csr    = (int2*)w;  w += align16((size_t)E * 8);
    unsigned short* xb   = (unsigned short*)w; w += align16((size_t)n * 384 * 2);
    unsigned short* hw1  = (unsigned short*)w; w += align16((size_t)n * DH * 2);
    unsigned short* proj = (unsigned short*)w; w += align16((size_t)n * DH * 2);
    unsigned short* hbuf = (unsigned short*)w; w += align16((size_t)n * DH * 2);
    unsigned short* Wp   = (unsigned short*)w; w += align16((size_t)131072 * 2);
    unsigned short* Wp1 = Wp;
    unsigned short* Wpr = Wp + 49152;
    unsigned short* Wp2 = Wp + 98304;
    unsigned short* WpM = Wp + 114688;
    unsigned short* hw2  = hw1;   // free after gfuse1
    unsigned short* h2   = proj;  // free after gfuse1
    unsigned short* zraw = hbuf;  // free after gfuse2

    int gE = (E + 255) / 256;
    int gN = (n + 255) / 256;
    int nb = (n + 1023) / 1024;
    dim3 gG((n + 127) / 128, 2);
    int gRow4 = (n + 3) / 4;

    // x -> bf16 (pure streaming) + weight repack
    conv_x_k<<<2048, 256, 0, stream>>>(x, xb, (long long)n * 48);
    repack_all_k<<<512, 256, 0, stream>>>(W1, rW, W2, mW1, Wp);

    // CSR build
    zero_int_k<<<gN, 256, 0, stream>>>(deg, n);
    deg_count_k<<<gE, 256, 0, stream>>>(dst, deg, E);
    dinv_k<<<gN, 256, 0, stream>>>(deg, dinv, n);
    scan_part_k<<<nb, 1024, 0, stream>>>(deg, rowptr, bsum, n);
    scan_top_k<<<1, 64, 0, stream>>>(bsum, rowptr + n, nb);
    scan_add_k<<<gN, 256, 0, stream>>>(bsum, rowptr, cursor, n);
    fill_k<<<gE, 256, 0, stream>>>(src, dst, dinv, cursor, csr, E);

    // layer 1
    mfma_gemm<384, true><<<gG, 256, 0, stream>>>(xb, Wp1, nullptr, Wpr, rb, hw1, proj, n);
    gfuse1_k<<<gRow4, 256, 0, stream>>>((unsigned*)hw1, (unsigned*)proj, rowptr, csr, dinv,
                                        b1, g1, be1, rg, rbe, (unsigned*)hbuf, n);

    // layer 2
    mfma_gemm<128, false><<<gG, 256, 0, stream>>>(hbuf, Wp2, nullptr, nullptr, nullptr, hw2, nullptr, n);
    gfuse2_k<<<gRow4, 256, 0, stream>>>((unsigned*)hw2, (unsigned*)hbuf, rowptr, csr, dinv,
                                        b2, g2, be2, (unsigned*)h2, n);

    // MLP head + softmax
    mfma_gemm<128, false><<<gG, 256, 0, stream>>>(h2, WpM, mb1, nullptr, nullptr, zraw, nullptr, n);
    head_k<<<gRow4, 256, 0, stream>>>((unsigned*)zraw, mg, mbe, mW2, mb2, out, n);
}

// Round 7
// 443.596 us; speedup vs baseline: 1.0294x; 1.0294x over previous
//
#include <hip/hip_runtime.h>

#define DH 128

typedef __attribute__((ext_vector_type(8))) short short8;
typedef __attribute__((ext_vector_type(4))) float f32x4;

// ---------- helpers ----------
__device__ __forceinline__ float wave_sum(float v) {
    #pragma unroll
    for (int o = 32; o > 0; o >>= 1) v += __shfl_xor(v, o, 64);
    return v;
}

__device__ __forceinline__ void ln_pair(float v0, float v1, float& o0, float& o1) {
    float m = wave_sum(v0 + v1) * (1.f / 128.f);
    float d0 = v0 - m, d1 = v1 - m;
    float var = wave_sum(d0 * d0 + d1 * d1) * (1.f / 128.f);
    float inv = rsqrtf(var + 1e-5f);
    o0 = d0 * inv; o1 = d1 * inv;
}

__device__ __forceinline__ float elu(float x) { return x > 0.f ? x : expm1f(x); }

// fp32 -> bf16 round-to-nearest-even
__device__ __forceinline__ unsigned short f2bf(float f) {
    unsigned u = __float_as_uint(f);
    u += 0x7fffu + ((u >> 16) & 1u);
    return (unsigned short)(u >> 16);
}
__device__ __forceinline__ float bfl(unsigned u) { return __uint_as_float(u << 16); }
__device__ __forceinline__ float bfh(unsigned u) { return __uint_as_float(u & 0xffff0000u); }
__device__ __forceinline__ unsigned pack_bf2(float a, float b) {
    return (unsigned)f2bf(a) | ((unsigned)f2bf(b) << 16);
}
__device__ __forceinline__ short8 cvt8(float4 v0, float4 v1) {
    short8 o;
    o[0] = (short)f2bf(v0.x); o[1] = (short)f2bf(v0.y);
    o[2] = (short)f2bf(v0.z); o[3] = (short)f2bf(v0.w);
    o[4] = (short)f2bf(v1.x); o[5] = (short)f2bf(v1.y);
    o[6] = (short)f2bf(v1.z); o[7] = (short)f2bf(v1.w);
    return o;
}

// ---------- streaming fp32 -> bf16 conversion of x ----------
__global__ __launch_bounds__(256) void conv_x_k(const float* __restrict__ x,
                                                unsigned short* __restrict__ xb,
                                                long long n8)
{
    long long i = (long long)blockIdx.x * 256 + threadIdx.x;
    long long stride = (long long)gridDim.x * 256;
    for (; i < n8; i += stride) {
        float4 v0 = *(const float4*)(x + i * 8);
        float4 v1 = *(const float4*)(x + i * 8 + 4);
        *(short8*)(xb + i * 8) = cvt8(v0, v1);
    }
}

// ---------- utility kernels ----------
__global__ void zero_int_k(int* __restrict__ p, int n) {
    int i = blockIdx.x * 256 + threadIdx.x;
    if (i < n) p[i] = 0;
}

__global__ void deg_count_k(const int* __restrict__ dst, int* __restrict__ deg, int E) {
    int e = blockIdx.x * 256 + threadIdx.x;
    if (e < E) atomicAdd(&deg[dst[e]], 1);
}

// ---------- parallel exclusive scan (3 kernels); also emits dinv ----------
__global__ __launch_bounds__(1024) void scan_part_k(const int* __restrict__ deg,
                                                    int* __restrict__ rowptr,
                                                    int* __restrict__ bsum,
                                                    float* __restrict__ dinv, int n)
{
    __shared__ int wsum[16];
    const int tid = threadIdx.x, lane = tid & 63, wid = tid >> 6;
    int i = blockIdx.x * 1024 + tid;
    int v = (i < n) ? deg[i] : 0;
    if (i < n) dinv[i] = rsqrtf((float)(v + 1));  // +1 self-loop
    int s = v;
    #pragma unroll
    for (int o = 1; o < 64; o <<= 1) {
        int t = __shfl_up(s, o, 64);
        if (lane >= o) s += t;
    }
    if (lane == 63) wsum[wid] = s;
    __syncthreads();
    if (tid < 16) {
        int ws = wsum[tid];
        #pragma unroll
        for (int o = 1; o < 16; o <<= 1) {
            int t = __shfl_up(ws, o, 64);
            if (tid >= o) ws += t;
        }
        wsum[tid] = ws;
    }
    __syncthreads();
    int excl = (wid ? wsum[wid - 1] : 0) + s - v;
    if (i < n) rowptr[i] = excl;
    if (tid == 0) bsum[blockIdx.x] = wsum[15];
}

__global__ void scan_top_k(int* __restrict__ bsum, int* __restrict__ rowptr_n, int nb) {
    int lane = threadIdx.x;  // blockDim = 64
    int carry = 0;
    for (int base = 0; base < nb; base += 64) {
        int i = base + lane;
        int v = (i < nb) ? bsum[i] : 0;
        int s = v;
        #pragma unroll
        for (int o = 1; o < 64; o <<= 1) {
            int t = __shfl_up(s, o, 64);
            if (lane >= o) s += t;
        }
        if (i < nb) bsum[i] = carry + s - v;
        carry += __shfl(s, 63, 64);
    }
    if (lane == 0) *rowptr_n = carry;
}

__global__ void scan_add_k(const int* __restrict__ bsum, int* __restrict__ rowptr,
                           int* __restrict__ cursor, int n)
{
    int i = blockIdx.x * 256 + threadIdx.x;
    if (i < n) {
        int v = rowptr[i] + bsum[i >> 10];
        rowptr[i] = v;
        cursor[i] = v;
    }
}

__global__ void fill_k(const int* __restrict__ src, const int* __restrict__ dst,
                       const float* __restrict__ dinv, int* __restrict__ cursor,
                       int2* __restrict__ csr, int E)
{
    int e = blockIdx.x * 256 + threadIdx.x;
    if (e < E) {
        int s = src[e], d = dst[e];
        float w = dinv[s] * dinv[d];
        int p = atomicAdd(&cursor[d], 1);
        csr[p] = make_int2(s, __float_as_int(w));
    }
}

// repack all four W's fp32 -> bf16 fragment panels [kb][n][32] into one buffer
__global__ void repack_all_k(const float* __restrict__ W1, const float* __restrict__ rW,
                             const float* __restrict__ W2, const float* __restrict__ mW1,
                             unsigned short* __restrict__ Wp)
{
    int idx = blockIdx.x * 256 + threadIdx.x;
    if (idx >= 131072) return;
    const float* W; int base;
    if (idx < 49152)       { W = W1;  base = 0; }
    else if (idx < 98304)  { W = rW;  base = 49152; }
    else if (idx < 114688) { W = W2;  base = 98304; }
    else                   { W = mW1; base = 114688; }
    int l = idx - base;
    int kb = l >> 12, rem = l & 4095;
    int nn = rem >> 5, ki = rem & 31;
    Wp[idx] = f2bf(W[(kb * 32 + ki) * DH + nn]);
}

// ---------- LDS-free-K-loop MFMA GEMM, 64-row tiles, coalesced LDS epilogue ----------
// grid (ceil(n/64), 2). Wave w: rows bx*64 + w*16 .. +16, cols by*64 .. +64.
template<int K, bool DUAL>
__global__ __launch_bounds__(256) void mfma_gemm(
    const unsigned short* __restrict__ A,
    const unsigned short* __restrict__ Bp1, const float* __restrict__ ba,
    const unsigned short* __restrict__ Bp2, const float* __restrict__ bb,
    unsigned short* __restrict__ outa, unsigned short* __restrict__ outb, int n)
{
    constexpr int NKB = K / 32;
    constexpr int LEP = 72;   // epilogue LDS row pitch (ushorts); 144 B, 16B-aligned
    __shared__ unsigned short sEp[64 * LEP];

    const int tid = threadIdx.x;
    const int wid = tid >> 6, lane = tid & 63;
    const int m16 = lane & 15, q = lane >> 4;
    const long long rowbase = (long long)blockIdx.x * 64;
    const int colb = blockIdx.y * 64;

    long long r0 = rowbase + wid * 16 + m16;
    if (r0 > (long long)n - 1) r0 = n - 1;

    f32x4 acc1[4], acc2[4];
    const f32x4 zero = {0.f, 0.f, 0.f, 0.f};
    #pragma unroll
    for (int j = 0; j < 4; j++) { acc1[j] = zero; if constexpr (DUAL) acc2[j] = zero; }

    short8 ha[3];                 // A: depth-2 prefetch
    short8 pb1[2][4], pb2[2][4];  // B: depth-1

    auto fetchA = [&](int kb, int buf) {
        ha[buf] = *(const short8*)(A + r0 * K + kb * 32 + q * 8);
    };
    auto fetchB = [&](int kb, int buf) {
        #pragma unroll
        for (int nj = 0; nj < 4; ++nj) {
            long long boff = ((long long)kb * 128 + colb + nj * 16 + m16) * 32 + q * 8;
            pb1[buf][nj] = *(const short8*)(Bp1 + boff);
            if constexpr (DUAL) pb2[buf][nj] = *(const short8*)(Bp2 + boff);
        }
    };

    fetchA(0, 0);
    fetchB(0, 0);
    if constexpr (NKB > 1) fetchA(1, 1);

    #pragma unroll
    for (int kb = 0; kb < NKB; ++kb) {
        if (kb + 2 < NKB) fetchA(kb + 2, (kb + 2) % 3);
        if (kb + 1 < NKB) fetchB(kb + 1, (kb + 1) & 1);
        const int ca = kb % 3, cb = kb & 1;
        #pragma unroll
        for (int nj = 0; nj < 4; ++nj) {
            acc1[nj] = __builtin_amdgcn_mfma_f32_16x16x32_bf16(ha[ca], pb1[cb][nj], acc1[nj], 0, 0, 0);
            if constexpr (DUAL)
                acc2[nj] = __builtin_amdgcn_mfma_f32_16x16x32_bf16(ha[ca], pb2[cb][nj], acc2[nj], 0, 0, 0);
        }
    }

    // ---- epilogue via LDS: C/D layout col=lane&15, row=(lane>>4)*4+reg ----
    // pass 1: acc1 -> sEp -> coalesced bf16 stores to outa
    #pragma unroll
    for (int nj = 0; nj < 4; ++nj) {
        int cl = nj * 16 + m16;
        float bav = ba ? ba[colb + cl] : 0.f;
        #pragma unroll
        for (int r = 0; r < 4; ++r)
            sEp[(wid * 16 + q * 4 + r) * LEP + cl] = f2bf(acc1[nj][r] + bav);
    }
    __syncthreads();
    #pragma unroll
    for (int h = 0; h < 2; ++h) {
        int idx = tid + h * 256;
        int row = idx >> 3, c8 = idx & 7;
        long long grow = rowbase + row;
        if (grow < n)
            *(short8*)(outa + grow * DH + colb + c8 * 8) = *(const short8*)(sEp + row * LEP + c8 * 8);
    }
    if constexpr (DUAL) {
        __syncthreads();
        #pragma unroll
        for (int nj = 0; nj < 4; ++nj) {
            int cl = nj * 16 + m16;
            float bbv = bb ? bb[colb + cl] : 0.f;
            #pragma unroll
            for (int r = 0; r < 4; ++r)
                sEp[(wid * 16 + q * 4 + r) * LEP + cl] = f2bf(acc2[nj][r] + bbv);
        }
        __syncthreads();
        #pragma unroll
        for (int h = 0; h < 2; ++h) {
            int idx = tid + h * 256;
            int row = idx >> 3, c8 = idx & 7;
            long long grow = rowbase + row;
            if (grow < n)
                *(short8*)(outb + grow * DH + colb + c8 * 8) = *(const short8*)(sEp + row * LEP + c8 * 8);
        }
    }
}

// ---------- CSR gather (bf16 rows), one wave per row, 8 loads in flight ----------
__device__ __forceinline__ void gather_row(
    const unsigned* __restrict__ hw, const int2* __restrict__ csr,
    int beg, int end, int lane, float& o0, float& o1)
{
    float a0 = 0.f, a1 = 0.f, b0 = 0.f, b1 = 0.f;
    float c0 = 0.f, c1 = 0.f, d0 = 0.f, d1 = 0.f;
    int p = beg;
    for (; p + 7 < end; p += 8) {
        int2 e0 = csr[p],     e1 = csr[p + 1], e2 = csr[p + 2], e3 = csr[p + 3];
        int2 e4 = csr[p + 4], e5 = csr[p + 5], e6 = csr[p + 6], e7 = csr[p + 7];
        unsigned u0 = hw[(long long)e0.x * 64 + lane];
        unsigned u1 = hw[(long long)e1.x * 64 + lane];
        unsigned u2 = hw[(long long)e2.x * 64 + lane];
        unsigned u3 = hw[(long long)e3.x * 64 + lane];
        unsigned u4 = hw[(long long)e4.x * 64 + lane];
        unsigned u5 = hw[(long long)e5.x * 64 + lane];
        unsigned u6 = hw[(long long)e6.x * 64 + lane];
        unsigned u7 = hw[(long long)e7.x * 64 + lane];
        float w0 = __int_as_float(e0.y), w1 = __int_as_float(e1.y);
        float w2 = __int_as_float(e2.y), w3 = __int_as_float(e3.y);
        float w4 = __int_as_float(e4.y), w5 = __int_as_float(e5.y);
        float w6 = __int_as_float(e6.y), w7 = __int_as_float(e7.y);
        a0 = fmaf(w0, bfl(u0), a0);  a1 = fmaf(w0, bfh(u0), a1);
        b0 = fmaf(w1, bfl(u1), b0);  b1 = fmaf(w1, bfh(u1), b1);
        c0 = fmaf(w2, bfl(u2), c0);  c1 = fmaf(w2, bfh(u2), c1);
        d0 = fmaf(w3, bfl(u3), d0);  d1 = fmaf(w3, bfh(u3), d1);
        a0 = fmaf(w4, bfl(u4), a0);  a1 = fmaf(w4, bfh(u4), a1);
        b0 = fmaf(w5, bfl(u5), b0);  b1 = fmaf(w5, bfh(u5), b1);
        c0 = fmaf(w6, bfl(u6), c0);  c1 = fmaf(w6, bfh(u6), c1);
        d0 = fmaf(w7, bfl(u7), d0);  d1 = fmaf(w7, bfh(u7), d1);
    }
    for (; p + 3 < end; p += 4) {
        int2 e0 = csr[p], e1 = csr[p + 1], e2 = csr[p + 2], e3 = csr[p + 3];
        unsigned u0 = hw[(long long)e0.x * 64 + lane];
        unsigned u1 = hw[(long long)e1.x * 64 + lane];
        unsigned u2 = hw[(long long)e2.x * 64 + lane];
        unsigned u3 = hw[(long long)e3.x * 64 + lane];
        float w0 = __int_as_float(e0.y), w1 = __int_as_float(e1.y);
        float w2 = __int_as_float(e2.y), w3 = __int_as_float(e3.y);
        a0 = fmaf(w0, bfl(u0), a0);  a1 = fmaf(w0, bfh(u0), a1);
        b0 = fmaf(w1, bfl(u1), b0);  b1 = fmaf(w1, bfh(u1), b1);
        c0 = fmaf(w2, bfl(u2), c0);  c1 = fmaf(w2, bfh(u2), c1);
        d0 = fmaf(w3, bfl(u3), d0);  d1 = fmaf(w3, bfh(u3), d1);
    }
    for (; p < end; ++p) {
        int2 e0 = csr[p];
        unsigned u0 = hw[(long long)e0.x * 64 + lane];
        float w0 = __int_as_float(e0.y);
        a0 = fmaf(w0, bfl(u0), a0);
        a1 = fmaf(w0, bfh(u0), a1);
    }
    o0 = (a0 + b0) + (c0 + d0);
    o1 = (a1 + b1) + (c1 + d1);
}

// layer 1: h = elu(LN(gather + dinv^2*hw + b1)) + LN(proj)
__global__ __launch_bounds__(256) void gfuse1_k(
    const unsigned* __restrict__ hw, const unsigned* __restrict__ proj,
    const int* __restrict__ rowptr, const int2* __restrict__ csr,
    const float* __restrict__ dinv,
    const float* __restrict__ b1, const float* __restrict__ g1, const float* __restrict__ be1,
    const float* __restrict__ rg, const float* __restrict__ rbe,
    unsigned* __restrict__ hout, int n)
{
    int row = blockIdx.x * 4 + (threadIdx.x >> 6);
    if (row >= n) return;
    int lane = threadIdx.x & 63;
    float a0, a1;
    gather_row(hw, csr, rowptr[row], rowptr[row + 1], lane, a0, a1);
    long long off = (long long)row * 64;
    float di = dinv[row], sl = di * di;
    unsigned us = hw[off + lane];
    float2 bv  = *(const float2*)(b1 + 2 * lane);
    float2 gv  = *(const float2*)(g1 + 2 * lane);
    float2 bev = *(const float2*)(be1 + 2 * lane);
    float2 rgv = *(const float2*)(rg + 2 * lane);
    float2 rbv = *(const float2*)(rbe + 2 * lane);
    float v0 = a0 + sl * bfl(us) + bv.x;
    float v1 = a1 + sl * bfh(us) + bv.y;
    float o0, o1; ln_pair(v0, v1, o0, o1);
    float t0 = elu(o0 * gv.x + bev.x);
    float t1 = elu(o1 * gv.y + bev.y);
    unsigned up = proj[off + lane];
    float q0, q1; ln_pair(bfl(up), bfh(up), q0, q1);
    hout[off + lane] = pack_bf2(t0 + q0 * rgv.x + rbv.x, t1 + q1 * rgv.y + rbv.y);
}

// layer 2: h2 = elu(LN(gather + dinv^2*hw + b2)) + hprev
__global__ __launch_bounds__(256) void gfuse2_k(
    const unsigned* __restrict__ hw, const unsigned* __restrict__ hprev,
    const int* __restrict__ rowptr, const int2* __restrict__ csr,
    const float* __restrict__ dinv,
    const float* __restrict__ b2, const float* __restrict__ g2, const float* __restrict__ be2,
    unsigned* __restrict__ h2, int n)
{
    int row = blockIdx.x * 4 + (threadIdx.x >> 6);
    if (row >= n) return;
    int lane = threadIdx.x & 63;
    float a0, a1;
    gather_row(hw, csr, rowptr[row], rowptr[row + 1], lane, a0, a1);
    long long off = (long long)row * 64;
    float di = dinv[row], sl = di * di;
    unsigned us = hw[off + lane];
    float2 bv  = *(const float2*)(b2 + 2 * lane);
    float2 gv  = *(const float2*)(g2 + 2 * lane);
    float2 bev = *(const float2*)(be2 + 2 * lane);
    float v0 = a0 + sl * bfl(us) + bv.x;
    float v1 = a1 + sl * bfh(us) + bv.y;
    float o0, o1; ln_pair(v0, v1, o0, o1);
    float t0 = elu(o0 * gv.x + bev.x);
    float t1 = elu(o1 * gv.y + bev.y);
    unsigned uh = hprev[off + lane];
    h2[off + lane] = pack_bf2(t0 + bfl(uh), t1 + bfh(uh));
}

// ---------- head: LN+ELU on zraw, z @ mW2 + mb2, softmax K=16 (fused) ----------
__global__ __launch_bounds__(256) void head_k(
    const unsigned* __restrict__ zraw, const float* __restrict__ g, const float* __restrict__ be,
    const float* __restrict__ mW2, const float* __restrict__ mb2,
    float* __restrict__ out, int n)
{
    int row = blockIdx.x * 4 + (threadIdx.x >> 6);
    if (row >= n) return;
    int lane = threadIdx.x & 63;
    unsigned u = zraw[(long long)row * 64 + lane];
    float o0, o1; ln_pair(bfl(u), bfh(u), o0, o1);
    float2 gv  = *(const float2*)(g + 2 * lane);
    float2 bev = *(const float2*)(be + 2 * lane);
    float z0 = elu(o0 * gv.x + bev.x);
    float z1 = elu(o1 * gv.y + bev.y);
    int k = lane & 15, seg = lane >> 4;
    float acc = 0.f;
    #pragma unroll
    for (int t = 0; t < 16; ++t) {
        int srcl = seg * 16 + t;
        float zz0 = __shfl(z0, srcl, 64);
        float zz1 = __shfl(z1, srcl, 64);
        int c = seg * 32 + 2 * t;
        acc = fmaf(zz0, mW2[c * 16 + k], acc);
        acc = fmaf(zz1, mW2[(c + 1) * 16 + k], acc);
    }
    acc += __shfl_xor(acc, 32, 64);
    acc += __shfl_xor(acc, 16, 64);
    float hk = acc + mb2[k];
    float mx = hk;
    #pragma unroll
    for (int o = 8; o > 0; o >>= 1) mx = fmaxf(mx, __shfl_xor(mx, o, 64));
    float e = expf(hk - mx);
    float s = e;
    #pragma unroll
    for (int o = 8; o > 0; o >>= 1) s += __shfl_xor(s, o, 64);
    if (lane < 16) out[(long long)row * 16 + k] = e / s;
}

// ---------- launcher ----------
static inline size_t align16(size_t x) { return (x + 15) & ~(size_t)15; }

extern "C" void kernel_launch(void* const* d_in, const int* in_sizes, int n_in,
                              void* d_out, int out_size, void* d_ws, size_t ws_size,
                              hipStream_t stream)
{
    const float* x   = (const float*)d_in[0];
    const int*   ei  = (const int*)d_in[1];
    const float* W1  = (const float*)d_in[2];
    const float* b1  = (const float*)d_in[3];
    const float* g1  = (const float*)d_in[4];
    const float* be1 = (const float*)d_in[5];
    const float* W2  = (const float*)d_in[6];
    const float* b2  = (const float*)d_in[7];
    const float* g2  = (const float*)d_in[8];
    const float* be2 = (const float*)d_in[9];
    const float* rW  = (const float*)d_in[10];
    const float* rb  = (const float*)d_in[11];
    const float* rg  = (const float*)d_in[12];
    const float* rbe = (const float*)d_in[13];
    const float* mW1 = (const float*)d_in[14];
    const float* mb1 = (const float*)d_in[15];
    const float* mg  = (const float*)d_in[16];
    const float* mbe = (const float*)d_in[17];
    const float* mW2 = (const float*)d_in[18];
    const float* mb2 = (const float*)d_in[19];
    float* out = (float*)d_out;

    const int n = in_sizes[0] / 384;
    const int E = in_sizes[1] / 2;
    const int* src = ei;
    const int* dst = ei + E;

    char* w = (char*)d_ws;
    int* deg     = (int*)w;   w += align16((size_t)n * 4);
    int* rowptr  = (int*)w;   w += align16((size_t)(n + 1) * 4);
    int* cursor  = (int*)w;   w += align16((size_t)n * 4);
    float* dinv  = (float*)w; w += align16((size_t)n * 4);
    int* bsum    = (int*)w;   w += align16((size_t)1024 * 4);
    int2* csr    = (int2*)w;  w += align16((size_t)E * 8);
    unsigned short* xb   = (unsigned short*)w; w += align16((size_t)n * 384 * 2);
    unsigned short* hw1  = (unsigned short*)w; w += align16((size_t)n * DH * 2);
    unsigned short* proj = (unsigned short*)w; w += align16((size_t)n * DH * 2);
    unsigned short* hbuf = (unsigned short*)w; w += align16((size_t)n * DH * 2);
    unsigned short* Wp   = (unsigned short*)w; w += align16((size_t)131072 * 2);
    unsigned short* Wp1 = Wp;
    unsigned short* Wpr = Wp + 49152;
    unsigned short* Wp2 = Wp + 98304;
    unsigned short* WpM = Wp + 114688;
    unsigned short* hw2  = hw1;   // free after gfuse1
    unsigned short* h2   = proj;  // free after gfuse1
    unsigned short* zraw = hbuf;  // free after gfuse2

    int gE = (E + 255) / 256;
    int gN = (n + 255) / 256;
    int nb = (n + 1023) / 1024;
    dim3 gG((n + 63) / 64, 2);
    int gRow4 = (n + 3) / 4;

    // x -> bf16 (pure streaming) + weight repack
    conv_x_k<<<2048, 256, 0, stream>>>(x, xb, (long long)n * 48);
    repack_all_k<<<512, 256, 0, stream>>>(W1, rW, W2, mW1, Wp);

    // CSR build
    zero_int_k<<<gN, 256, 0, stream>>>(deg, n);
    deg_count_k<<<gE, 256, 0, stream>>>(dst, deg, E);
    scan_part_k<<<nb, 1024, 0, stream>>>(deg, rowptr, bsum, dinv, n);
    scan_top_k<<<1, 64, 0, stream>>>(bsum, rowptr + n, nb);
    scan_add_k<<<gN, 256, 0, stream>>>(bsum, rowptr, cursor, n);
    fill_k<<<gE, 256, 0, stream>>>(src, dst, dinv, cursor, csr, E);

    // layer 1
    mfma_gemm<384, true><<<gG, 256, 0, stream>>>(xb, Wp1, nullptr, Wpr, rb, hw1, proj, n);
    gfuse1_k<<<gRow4, 256, 0, stream>>>((unsigned*)hw1, (unsigned*)proj, rowptr, csr, dinv,
                                        b1, g1, be1, rg, rbe, (unsigned*)hbuf, n);

    // layer 2
    mfma_gemm<128, false><<<gG, 256, 0, stream>>>(hbuf, Wp2, nullptr, nullptr, nullptr, hw2, nullptr, n);
    gfuse2_k<<<gRow4, 256, 0, stream>>>((unsigned*)hw2, (unsigned*)hbuf, rowptr, csr, dinv,
                                        b2, g2, be2, (unsigned*)h2, n);

    // MLP head + softmax
    mfma_gemm<128, false><<<gG, 256, 0, stream>>>(h2, WpM, mb1, nullptr, nullptr, zraw, nullptr, n);
    head_k<<<gRow4, 256, 0, stream>>>((unsigned*)zraw, mg, mbe, mW2, mb2, out, n);
}

// Round 8
// 434.478 us; speedup vs baseline: 1.0510x; 1.0210x over previous
//
#include <hip/hip_runtime.h>

#define DH 128

typedef __attribute__((ext_vector_type(8))) short short8;
typedef __attribute__((ext_vector_type(4))) float f32x4;

// ---------- helpers ----------
__device__ __forceinline__ float wave_sum(float v) {
    #pragma unroll
    for (int o = 32; o > 0; o >>= 1) v += __shfl_xor(v, o, 64);
    return v;
}

__device__ __forceinline__ void ln_pair(float v0, float v1, float& o0, float& o1) {
    float m = wave_sum(v0 + v1) * (1.f / 128.f);
    float d0 = v0 - m, d1 = v1 - m;
    float var = wave_sum(d0 * d0 + d1 * d1) * (1.f / 128.f);
    float inv = rsqrtf(var + 1e-5f);
    o0 = d0 * inv; o1 = d1 * inv;
}

__device__ __forceinline__ float elu(float x) { return x > 0.f ? x : expm1f(x); }

// fp32 -> bf16 round-to-nearest-even
__device__ __forceinline__ unsigned short f2bf(float f) {
    unsigned u = __float_as_uint(f);
    u += 0x7fffu + ((u >> 16) & 1u);
    return (unsigned short)(u >> 16);
}
__device__ __forceinline__ float bfl(unsigned u) { return __uint_as_float(u << 16); }
__device__ __forceinline__ float bfh(unsigned u) { return __uint_as_float(u & 0xffff0000u); }
__device__ __forceinline__ unsigned pack_bf2(float a, float b) {
    return (unsigned)f2bf(a) | ((unsigned)f2bf(b) << 16);
}
__device__ __forceinline__ short8 cvt8(float4 v0, float4 v1) {
    short8 o;
    o[0] = (short)f2bf(v0.x); o[1] = (short)f2bf(v0.y);
    o[2] = (short)f2bf(v0.z); o[3] = (short)f2bf(v0.w);
    o[4] = (short)f2bf(v1.x); o[5] = (short)f2bf(v1.y);
    o[6] = (short)f2bf(v1.z); o[7] = (short)f2bf(v1.w);
    return o;
}

// ---------- streaming fp32 -> bf16 conversion of x ----------
__global__ __launch_bounds__(256) void conv_x_k(const float* __restrict__ x,
                                                unsigned short* __restrict__ xb,
                                                long long n8)
{
    long long i = (long long)blockIdx.x * 256 + threadIdx.x;
    long long stride = (long long)gridDim.x * 256;
    for (; i < n8; i += stride) {
        float4 v0 = *(const float4*)(x + i * 8);
        float4 v1 = *(const float4*)(x + i * 8 + 4);
        *(short8*)(xb + i * 8) = cvt8(v0, v1);
    }
}

// ---------- utility kernels ----------
__global__ void zero_int_k(int* __restrict__ p, int n) {
    int i = blockIdx.x * 256 + threadIdx.x;
    if (i < n) p[i] = 0;
}

__global__ void deg_count_k(const int* __restrict__ dst, int* __restrict__ deg, int E) {
    int e = blockIdx.x * 256 + threadIdx.x;
    if (e < E) atomicAdd(&deg[dst[e]], 1);
}

// ---------- parallel exclusive scan (3 kernels); also emits dinv ----------
__global__ __launch_bounds__(1024) void scan_part_k(const int* __restrict__ deg,
                                                    int* __restrict__ rowptr,
                                                    int* __restrict__ bsum,
                                                    float* __restrict__ dinv, int n)
{
    __shared__ int wsum[16];
    const int tid = threadIdx.x, lane = tid & 63, wid = tid >> 6;
    int i = blockIdx.x * 1024 + tid;
    int v = (i < n) ? deg[i] : 0;
    if (i < n) dinv[i] = rsqrtf((float)(v + 1));  // +1 self-loop
    int s = v;
    #pragma unroll
    for (int o = 1; o < 64; o <<= 1) {
        int t = __shfl_up(s, o, 64);
        if (lane >= o) s += t;
    }
    if (lane == 63) wsum[wid] = s;
    __syncthreads();
    if (tid < 16) {
        int ws = wsum[tid];
        #pragma unroll
        for (int o = 1; o < 16; o <<= 1) {
            int t = __shfl_up(ws, o, 64);
            if (tid >= o) ws += t;
        }
        wsum[tid] = ws;
    }
    __syncthreads();
    int excl = (wid ? wsum[wid - 1] : 0) + s - v;
    if (i < n) rowptr[i] = excl;
    if (tid == 0) bsum[blockIdx.x] = wsum[15];
}

__global__ void scan_top_k(int* __restrict__ bsum, int* __restrict__ rowptr_n, int nb) {
    int lane = threadIdx.x;  // blockDim = 64
    int carry = 0;
    for (int base = 0; base < nb; base += 64) {
        int i = base + lane;
        int v = (i < nb) ? bsum[i] : 0;
        int s = v;
        #pragma unroll
        for (int o = 1; o < 64; o <<= 1) {
            int t = __shfl_up(s, o, 64);
            if (lane >= o) s += t;
        }
        if (i < nb) bsum[i] = carry + s - v;
        carry += __shfl(s, 63, 64);
    }
    if (lane == 0) *rowptr_n = carry;
}

__global__ void scan_add_k(const int* __restrict__ bsum, int* __restrict__ rowptr,
                           int* __restrict__ cursor, int n)
{
    int i = blockIdx.x * 256 + threadIdx.x;
    if (i < n) {
        int v = rowptr[i] + bsum[i >> 10];
        rowptr[i] = v;
        cursor[i] = v;
    }
}

__global__ void fill_k(const int* __restrict__ src, const int* __restrict__ dst,
                       const float* __restrict__ dinv, int* __restrict__ cursor,
                       int2* __restrict__ csr, int E)
{
    int e = blockIdx.x * 256 + threadIdx.x;
    if (e < E) {
        int s = src[e], d = dst[e];
        float w = dinv[s] * dinv[d];
        int p = atomicAdd(&cursor[d], 1);
        csr[p] = make_int2(s, __float_as_int(w));
    }
}

// repack all four W's fp32 -> bf16 fragment panels [kb][n][32] into one buffer
__global__ void repack_all_k(const float* __restrict__ W1, const float* __restrict__ rW,
                             const float* __restrict__ W2, const float* __restrict__ mW1,
                             unsigned short* __restrict__ Wp)
{
    int idx = blockIdx.x * 256 + threadIdx.x;
    if (idx >= 131072) return;
    const float* W; int base;
    if (idx < 49152)       { W = W1;  base = 0; }
    else if (idx < 98304)  { W = rW;  base = 49152; }
    else if (idx < 114688) { W = W2;  base = 98304; }
    else                   { W = mW1; base = 114688; }
    int l = idx - base;
    int kb = l >> 12, rem = l & 4095;
    int nn = rem >> 5, ki = rem & 31;
    Wp[idx] = f2bf(W[(kb * 32 + ki) * DH + nn]);
}

// ---------- MFMA GEMM: B panel resident in LDS, barrier-free K-loop ----------
// grid (ceil(n/128), 2*NMAT). Block: 128 rows x 64 cols of matrix (by>>1),
// col-half (by&1). Wave w: rows +w*32..+32 (2 A-frags), all 64 cols.
// B staged to LDS once (1 barrier); K-loop: 2 global A (depth-2 prefetch) +
// 4 ds_read_b128 + 8 MFMA per iter, no barriers. smem reused for epilogue.
template<int K, int NMAT>
__global__ __launch_bounds__(256, 3) void mfma_gemm(
    const unsigned short* __restrict__ A,
    const unsigned short* __restrict__ Bp1, const float* __restrict__ ba,
    const unsigned short* __restrict__ Bp2, const float* __restrict__ bb,
    unsigned short* __restrict__ outa, unsigned short* __restrict__ outb, int n)
{
    constexpr int NKB = K / 32;
    constexpr int SB   = NKB * 64 * 32;   // B panel shorts ([kb][cl][32])
    constexpr int SEP  = 128 * 72;        // epilogue shorts (pitch 72)
    constexpr int SMEM = SB > SEP ? SB : SEP;
    __shared__ __align__(16) unsigned short smem[SMEM];

    const int tid = threadIdx.x;
    const int wid = tid >> 6, lane = tid & 63;
    const int m16 = lane & 15, q = lane >> 4;
    const int mat = (NMAT == 2) ? (int)(blockIdx.y >> 1) : 0;
    const int c0  = (blockIdx.y & 1) * 64;
    const unsigned short* Bp = mat ? Bp2 : Bp1;
    unsigned short* outp = mat ? outb : outa;
    const float* bias = mat ? bb : ba;
    const long long rowbase = (long long)blockIdx.x * 128;

    long long r0 = rowbase + wid * 32 + m16;       if (r0 > (long long)n - 1) r0 = n - 1;
    long long r1 = rowbase + wid * 32 + 16 + m16;  if (r1 > (long long)n - 1) r1 = n - 1;

    f32x4 acc[2][4];
    const f32x4 zero = {0.f, 0.f, 0.f, 0.f};
    #pragma unroll
    for (int mi = 0; mi < 2; ++mi)
        #pragma unroll
        for (int nj = 0; nj < 4; ++nj) acc[mi][nj] = zero;

    short8 ha[3][2];   // A: depth-2 prefetch (rotating)
    short8 bf[2][4];   // B frags from LDS: depth-1

    auto fetchA = [&](int kb, int buf) {
        ha[buf][0] = *(const short8*)(A + r0 * K + kb * 32 + q * 8);
        ha[buf][1] = *(const short8*)(A + r1 * K + kb * 32 + q * 8);
    };
    auto fetchB = [&](int kb, int buf) {
        #pragma unroll
        for (int nj = 0; nj < 4; ++nj)
            bf[buf][nj] = *(const short8*)(smem + kb * 2048 + (nj * 16 + m16) * 32 + q * 8);
    };

    // start A prefetch before staging B (overlap global latency with stage)
    fetchA(0, 0);
    if constexpr (NKB > 1) fetchA(1, 1);

    // stage B panel: [kb][cl][32] <- Bp[kb][c0+cl][32]
    #pragma unroll
    for (int t = tid; t < K * 8; t += 256) {   // short8 units
        int k8 = t & 3, cl = (t >> 2) & 63, kb = t >> 8;
        *(short8*)(smem + kb * 2048 + cl * 32 + k8 * 8) =
            *(const short8*)(Bp + (long long)kb * 4096 + (c0 + cl) * 32 + k8 * 8);
    }
    __syncthreads();

    fetchB(0, 0);
    #pragma unroll
    for (int kb = 0; kb < NKB; ++kb) {
        if (kb + 2 < NKB) fetchA(kb + 2, (kb + 2) % 3);
        if (kb + 1 < NKB) fetchB(kb + 1, (kb + 1) & 1);
        const int ca = kb % 3, cb = kb & 1;
        #pragma unroll
        for (int mi = 0; mi < 2; ++mi)
            #pragma unroll
            for (int nj = 0; nj < 4; ++nj)
                acc[mi][nj] = __builtin_amdgcn_mfma_f32_16x16x32_bf16(ha[ca][mi], bf[cb][nj], acc[mi][nj], 0, 0, 0);
    }

    // ---- epilogue via smem (reuse B panel space): coalesced bf16 stores ----
    __syncthreads();   // all waves done reading B
    #pragma unroll
    for (int nj = 0; nj < 4; ++nj) {
        int cl = nj * 16 + m16;
        float bv = bias ? bias[c0 + cl] : 0.f;
        #pragma unroll
        for (int mi = 0; mi < 2; ++mi)
            #pragma unroll
            for (int r = 0; r < 4; ++r)
                smem[(wid * 32 + mi * 16 + q * 4 + r) * 72 + cl] = f2bf(acc[mi][nj][r] + bv);
    }
    __syncthreads();
    #pragma unroll
    for (int h = 0; h < 4; ++h) {
        int idx = tid + h * 256;
        int row = idx >> 3, c8 = idx & 7;
        long long grow = rowbase + row;
        if (grow < n)
            *(short8*)(outp + grow * DH + c0 + c8 * 8) = *(const short8*)(smem + row * 72 + c8 * 8);
    }
}

// ---------- CSR gather (bf16 rows), one wave per row, 8 loads in flight ----------
__device__ __forceinline__ void gather_row(
    const unsigned* __restrict__ hw, const int2* __restrict__ csr,
    int beg, int end, int lane, float& o0, float& o1)
{
    float a0 = 0.f, a1 = 0.f, b0 = 0.f, b1 = 0.f;
    float c0 = 0.f, c1 = 0.f, d0 = 0.f, d1 = 0.f;
    int p = beg;
    for (; p + 7 < end; p += 8) {
        int2 e0 = csr[p],     e1 = csr[p + 1], e2 = csr[p + 2], e3 = csr[p + 3];
        int2 e4 = csr[p + 4], e5 = csr[p + 5], e6 = csr[p + 6], e7 = csr[p + 7];
        unsigned u0 = hw[(long long)e0.x * 64 + lane];
        unsigned u1 = hw[(long long)e1.x * 64 + lane];
        unsigned u2 = hw[(long long)e2.x * 64 + lane];
        unsigned u3 = hw[(long long)e3.x * 64 + lane];
        unsigned u4 = hw[(long long)e4.x * 64 + lane];
        unsigned u5 = hw[(long long)e5.x * 64 + lane];
        unsigned u6 = hw[(long long)e6.x * 64 + lane];
        unsigned u7 = hw[(long long)e7.x * 64 + lane];
        float w0 = __int_as_float(e0.y), w1 = __int_as_float(e1.y);
        float w2 = __int_as_float(e2.y), w3 = __int_as_float(e3.y);
        float w4 = __int_as_float(e4.y), w5 = __int_as_float(e5.y);
        float w6 = __int_as_float(e6.y), w7 = __int_as_float(e7.y);
        a0 = fmaf(w0, bfl(u0), a0);  a1 = fmaf(w0, bfh(u0), a1);
        b0 = fmaf(w1, bfl(u1), b0);  b1 = fmaf(w1, bfh(u1), b1);
        c0 = fmaf(w2, bfl(u2), c0);  c1 = fmaf(w2, bfh(u2), c1);
        d0 = fmaf(w3, bfl(u3), d0);  d1 = fmaf(w3, bfh(u3), d1);
        a0 = fmaf(w4, bfl(u4), a0);  a1 = fmaf(w4, bfh(u4), a1);
        b0 = fmaf(w5, bfl(u5), b0);  b1 = fmaf(w5, bfh(u5), b1);
        c0 = fmaf(w6, bfl(u6), c0);  c1 = fmaf(w6, bfh(u6), c1);
        d0 = fmaf(w7, bfl(u7), d0);  d1 = fmaf(w7, bfh(u7), d1);
    }
    for (; p + 3 < end; p += 4) {
        int2 e0 = csr[p], e1 = csr[p + 1], e2 = csr[p + 2], e3 = csr[p + 3];
        unsigned u0 = hw[(long long)e0.x * 64 + lane];
        unsigned u1 = hw[(long long)e1.x * 64 + lane];
        unsigned u2 = hw[(long long)e2.x * 64 + lane];
        unsigned u3 = hw[(long long)e3.x * 64 + lane];
        float w0 = __int_as_float(e0.y), w1 = __int_as_float(e1.y);
        float w2 = __int_as_float(e2.y), w3 = __int_as_float(e3.y);
        a0 = fmaf(w0, bfl(u0), a0);  a1 = fmaf(w0, bfh(u0), a1);
        b0 = fmaf(w1, bfl(u1), b0);  b1 = fmaf(w1, bfh(u1), b1);
        c0 = fmaf(w2, bfl(u2), c0);  c1 = fmaf(w2, bfh(u2), c1);
        d0 = fmaf(w3, bfl(u3), d0);  d1 = fmaf(w3, bfh(u3), d1);
    }
    for (; p < end; ++p) {
        int2 e0 = csr[p];
        unsigned u0 = hw[(long long)e0.x * 64 + lane];
        float w0 = __int_as_float(e0.y);
        a0 = fmaf(w0, bfl(u0), a0);
        a1 = fmaf(w0, bfh(u0), a1);
    }
    o0 = (a0 + b0) + (c0 + d0);
    o1 = (a1 + b1) + (c1 + d1);
}

// layer 1: h = elu(LN(gather + dinv^2*hw + b1)) + LN(proj)
__global__ __launch_bounds__(256) void gfuse1_k(
    const unsigned* __restrict__ hw, const unsigned* __restrict__ proj,
    const int* __restrict__ rowptr, const int2* __restrict__ csr,
    const float* __restrict__ dinv,
    const float* __restrict__ b1, const float* __restrict__ g1, const float* __restrict__ be1,
    const float* __restrict__ rg, const float* __restrict__ rbe,
    unsigned* __restrict__ hout, int n)
{
    int row = blockIdx.x * 4 + (threadIdx.x >> 6);
    if (row >= n) return;
    int lane = threadIdx.x & 63;
    float a0, a1;
    gather_row(hw, csr, rowptr[row], rowptr[row + 1], lane, a0, a1);
    long long off = (long long)row * 64;
    float di = dinv[row], sl = di * di;
    unsigned us = hw[off + lane];
    float2 bv  = *(const float2*)(b1 + 2 * lane);
    float2 gv  = *(const float2*)(g1 + 2 * lane);
    float2 bev = *(const float2*)(be1 + 2 * lane);
    float2 rgv = *(const float2*)(rg + 2 * lane);
    float2 rbv = *(const float2*)(rbe + 2 * lane);
    float v0 = a0 + sl * bfl(us) + bv.x;
    float v1 = a1 + sl * bfh(us) + bv.y;
    float o0, o1; ln_pair(v0, v1, o0, o1);
    float t0 = elu(o0 * gv.x + bev.x);
    float t1 = elu(o1 * gv.y + bev.y);
    unsigned up = proj[off + lane];
    float q0, q1; ln_pair(bfl(up), bfh(up), q0, q1);
    hout[off + lane] = pack_bf2(t0 + q0 * rgv.x + rbv.x, t1 + q1 * rgv.y + rbv.y);
}

// layer 2: h2 = elu(LN(gather + dinv^2*hw + b2)) + hprev
__global__ __launch_bounds__(256) void gfuse2_k(
    const unsigned* __restrict__ hw, const unsigned* __restrict__ hprev,
    const int* __restrict__ rowptr, const int2* __restrict__ csr,
    const float* __restrict__ dinv,
    const float* __restrict__ b2, const float* __restrict__ g2, const float* __restrict__ be2,
    unsigned* __restrict__ h2, int n)
{
    int row = blockIdx.x * 4 + (threadIdx.x >> 6);
    if (row >= n) return;
    int lane = threadIdx.x & 63;
    float a0, a1;
    gather_row(hw, csr, rowptr[row], rowptr[row + 1], lane, a0, a1);
    long long off = (long long)row * 64;
    float di = dinv[row], sl = di * di;
    unsigned us = hw[off + lane];
    float2 bv  = *(const float2*)(b2 + 2 * lane);
    float2 gv  = *(const float2*)(g2 + 2 * lane);
    float2 bev = *(const float2*)(be2 + 2 * lane);
    float v0 = a0 + sl * bfl(us) + bv.x;
    float v1 = a1 + sl * bfh(us) + bv.y;
    float o0, o1; ln_pair(v0, v1, o0, o1);
    float t0 = elu(o0 * gv.x + bev.x);
    float t1 = elu(o1 * gv.y + bev.y);
    unsigned uh = hprev[off + lane];
    h2[off + lane] = pack_bf2(t0 + bfl(uh), t1 + bfh(uh));
}

// ---------- head: LN+ELU on zraw, z @ mW2 + mb2, softmax K=16 (fused) ----------
__global__ __launch_bounds__(256) void head_k(
    const unsigned* __restrict__ zraw, const float* __restrict__ g, const float* __restrict__ be,
    const float* __restrict__ mW2, const float* __restrict__ mb2,
    float* __restrict__ out, int n)
{
    int row = blockIdx.x * 4 + (threadIdx.x >> 6);
    if (row >= n) return;
    int lane = threadIdx.x & 63;
    unsigned u = zraw[(long long)row * 64 + lane];
    float o0, o1; ln_pair(bfl(u), bfh(u), o0, o1);
    float2 gv  = *(const float2*)(g + 2 * lane);
    float2 bev = *(const float2*)(be + 2 * lane);
    float z0 = elu(o0 * gv.x + bev.x);
    float z1 = elu(o1 * gv.y + bev.y);
    int k = lane & 15, seg = lane >> 4;
    float acc = 0.f;
    #pragma unroll
    for (int t = 0; t < 16; ++t) {
        int srcl = seg * 16 + t;
        float zz0 = __shfl(z0, srcl, 64);
        float zz1 = __shfl(z1, srcl, 64);
        int c = seg * 32 + 2 * t;
        acc = fmaf(zz0, mW2[c * 16 + k], acc);
        acc = fmaf(zz1, mW2[(c + 1) * 16 + k], acc);
    }
    acc += __shfl_xor(acc, 32, 64);
    acc += __shfl_xor(acc, 16, 64);
    float hk = acc + mb2[k];
    float mx = hk;
    #pragma unroll
    for (int o = 8; o > 0; o >>= 1) mx = fmaxf(mx, __shfl_xor(mx, o, 64));
    float e = expf(hk - mx);
    float s = e;
    #pragma unroll
    for (int o = 8; o > 0; o >>= 1) s += __shfl_xor(s, o, 64);
    if (lane < 16) out[(long long)row * 16 + k] = e / s;
}

// ---------- launcher ----------
static inline size_t align16(size_t x) { return (x + 15) & ~(size_t)15; }

extern "C" void kernel_launch(void* const* d_in, const int* in_sizes, int n_in,
                              void* d_out, int out_size, void* d_ws, size_t ws_size,
                              hipStream_t stream)
{
    const float* x   = (const float*)d_in[0];
    const int*   ei  = (const int*)d_in[1];
    const float* W1  = (const float*)d_in[2];
    const float* b1  = (const float*)d_in[3];
    const float* g1  = (const float*)d_in[4];
    const float* be1 = (const float*)d_in[5];
    const float* W2  = (const float*)d_in[6];
    const float* b2  = (const float*)d_in[7];
    const float* g2  = (const float*)d_in[8];
    const float* be2 = (const float*)d_in[9];
    const float* rW  = (const float*)d_in[10];
    const float* rb  = (const float*)d_in[11];
    const float* rg  = (const float*)d_in[12];
    const float* rbe = (const float*)d_in[13];
    const float* mW1 = (const float*)d_in[14];
    const float* mb1 = (const float*)d_in[15];
    const float* mg  = (const float*)d_in[16];
    const float* mbe = (const float*)d_in[17];
    const float* mW2 = (const float*)d_in[18];
    const float* mb2 = (const float*)d_in[19];
    float* out = (float*)d_out;

    const int n = in_sizes[0] / 384;
    const int E = in_sizes[1] / 2;
    const int* src = ei;
    const int* dst = ei + E;

    char* w = (char*)d_ws;
    int* deg     = (int*)w;   w += align16((size_t)n * 4);
    int* rowptr  = (int*)w;   w += align16((size_t)(n + 1) * 4);
    int* cursor  = (int*)w;   w += align16((size_t)n * 4);
    float* dinv  = (float*)w; w += align16((size_t)n * 4);
    int* bsum    = (int*)w;   w += align16((size_t)1024 * 4);
    int2* csr    = (int2*)w;  w += align16((size_t)E * 8);
    unsigned short* xb   = (unsigned short*)w; w += align16((size_t)n * 384 * 2);
    unsigned short* hw1  = (unsigned short*)w; w += align16((size_t)n * DH * 2);
    unsigned short* proj = (unsigned short*)w; w += align16((size_t)n * DH * 2);
    unsigned short* hbuf = (unsigned short*)w; w += align16((size_t)n * DH * 2);
    unsigned short* Wp   = (unsigned short*)w; w += align16((size_t)131072 * 2);
    unsigned short* Wp1 = Wp;
    unsigned short* Wpr = Wp + 49152;
    unsigned short* Wp2 = Wp + 98304;
    unsigned short* WpM = Wp + 114688;
    unsigned short* hw2  = hw1;   // free after gfuse1
    unsigned short* h2   = proj;  // free after gfuse1
    unsigned short* zraw = hbuf;  // free after gfuse2

    int gE = (E + 255) / 256;
    int gN = (n + 255) / 256;
    int nb = (n + 1023) / 1024;
    dim3 gGd((n + 127) / 128, 4);   // dual (matrix x col-half)
    dim3 gGs((n + 127) / 128, 2);   // single
    int gRow4 = (n + 3) / 4;

    // x -> bf16 (pure streaming) + weight repack
    conv_x_k<<<2048, 256, 0, stream>>>(x, xb, (long long)n * 48);
    repack_all_k<<<512, 256, 0, stream>>>(W1, rW, W2, mW1, Wp);

    // CSR build
    zero_int_k<<<gN, 256, 0, stream>>>(deg, n);
    deg_count_k<<<gE, 256, 0, stream>>>(dst, deg, E);
    scan_part_k<<<nb, 1024, 0, stream>>>(deg, rowptr, bsum, dinv, n);
    scan_top_k<<<1, 64, 0, stream>>>(bsum, rowptr + n, nb);
    scan_add_k<<<gN, 256, 0, stream>>>(bsum, rowptr, cursor, n);
    fill_k<<<gE, 256, 0, stream>>>(src, dst, dinv, cursor, csr, E);

    // layer 1 (dual: hw1 = xb@W1, proj = xb@rW + rb)
    mfma_gemm<384, 2><<<gGd, 256, 0, stream>>>(xb, Wp1, nullptr, Wpr, rb, hw1, proj, n);
    gfuse1_k<<<gRow4, 256, 0, stream>>>((unsigned*)hw1, (unsigned*)proj, rowptr, csr, dinv,
                                        b1, g1, be1, rg, rbe, (unsigned*)hbuf, n);

    // layer 2
    mfma_gemm<128, 1><<<gGs, 256, 0, stream>>>(hbuf, Wp2, nullptr, nullptr, nullptr, hw2, nullptr, n);
    gfuse2_k<<<gRow4, 256, 0, stream>>>((unsigned*)hw2, (unsigned*)hbuf, rowptr, csr, dinv,
                                        b2, g2, be2, (unsigned*)h2, n);

    // MLP head + softmax
    mfma_gemm<128, 1><<<gGs, 256, 0, stream>>>(h2, WpM, mb1, nullptr, nullptr, zraw, nullptr, n);
    head_k<<<gRow4, 256, 0, stream>>>((unsigned*)zraw, mg, mbe, mW2, mb2, out, n);
}